// Round 11
// baseline (271.854 us; speedup 1.0000x reference)
//
#include <hip/hip_runtime.h>
#include <hip/hip_bf16.h>

#define BB 4096
#define DD 1024
#define NBF 16
#define HH 2048
#define KK 16384   // DD*NBF (elements; also bytes for i8 rows)
#define NT 128     // K-tiles of 128 bytes
#define LN_EPS 1e-5f

typedef int   i32x4 __attribute__((ext_vector_type(4)));   // i8 MFMA A/B (16 i8) and C/D (4 i32)
typedef unsigned short us8 __attribute__((ext_vector_type(8)));

__device__ __forceinline__ unsigned short f2bf(float f) {
  union { float f; unsigned int u; } c; c.f = f;
  unsigned int u = c.u;
  return (unsigned short)((u + 0x7FFFu + ((u >> 16) & 1u)) >> 16);  // RNE
}
__device__ __forceinline__ float bf2f(unsigned short s) {
  union { unsigned int u; float f; } c; c.u = ((unsigned int)s) << 16;
  return c.f;
}
__device__ __forceinline__ float softplusf(float x) {
  return (x > 20.f) ? x : log1pf(expf(x));
}
__device__ __forceinline__ int pack4(int q0, int q1, int q2, int q3) {
  return (q0 & 0xff) | ((q1 & 0xff) << 8) | ((q2 & 0xff) << 16) | ((q3 & 0xff) << 24);
}

// cs[d*16+k] = centers[d][k] / (softplus(width[d]) + 1e-6)
__global__ void prep_kernel(const float* __restrict__ centers, const float* __restrict__ width,
                            float* __restrict__ cs) {
  const int i = blockIdx.x * 256 + threadIdx.x;  // 16384 total
  const int d = i >> 4;
  const float w = softplusf(width[d]) + 1e-6f;
  cs[i] = centers[i] / w;
}

// LayerNorm + triangular basis -> zq (i8 [B,KK], zq = round(127*phi)), and ylin[b]
__global__ __launch_bounds__(256)
void zexp_kernel(const float* __restrict__ x, const float* __restrict__ g,
                 const float* __restrict__ be, const float* __restrict__ width,
                 const float* __restrict__ sh_w, const float* __restrict__ sh_b,
                 const float* __restrict__ cs,
                 unsigned char* __restrict__ zq, float* __restrict__ ylin) {
  __shared__ float red[8];
  const int b = blockIdx.x, tid = threadIdx.x;
  const float4 v = ((const float4*)(x + (size_t)b * DD))[tid];
  float s  = v.x + v.y + v.z + v.w;
  float ss = v.x*v.x + v.y*v.y + v.z*v.z + v.w*v.w;
  #pragma unroll
  for (int off = 32; off > 0; off >>= 1) {
    s  += __shfl_xor(s, off);
    ss += __shfl_xor(ss, off);
  }
  if ((tid & 63) == 0) { red[(tid>>6)*2] = s; red[(tid>>6)*2+1] = ss; }
  __syncthreads();
  const float sum   = red[0]+red[2]+red[4]+red[6];
  const float sumsq = red[1]+red[3]+red[5]+red[7];
  const float mu   = sum * (1.f/DD);
  const float var  = sumsq * (1.f/DD) - mu*mu;
  const float rstd = rsqrtf(var + LN_EPS);
  const float4 g4 = ((const float4*)g)[tid];
  const float4 b4 = ((const float4*)be)[tid];
  const float4 w4 = ((const float4*)width)[tid];
  const float4 s4 = ((const float4*)sh_w)[tid];
  const float xn0 = (v.x - mu)*rstd*g4.x + b4.x;
  const float xn1 = (v.y - mu)*rstd*g4.y + b4.y;
  const float xn2 = (v.z - mu)*rstd*g4.z + b4.z;
  const float xn3 = (v.w - mu)*rstd*g4.w + b4.w;
  float xsv[4];
  xsv[0] = xn0 / (softplusf(w4.x) + 1e-6f);
  xsv[1] = xn1 / (softplusf(w4.y) + 1e-6f);
  xsv[2] = xn2 / (softplusf(w4.z) + 1e-6f);
  xsv[3] = xn3 / (softplusf(w4.w) + 1e-6f);
  unsigned char* zr = zq + (size_t)b * KK + tid * 64;
  #pragma unroll
  for (int j = 0; j < 4; ++j) {
    const float4* c4 = (const float4*)(cs + (tid * 4 + j) * 16);
    const float xv = xsv[j];
    int q[16];
    #pragma unroll
    for (int qq = 0; qq < 4; ++qq) {
      const float4 ca = c4[qq];
      q[qq*4+0] = __float2int_rn(fmaxf(0.f, 1.f - fabsf(xv - ca.x)) * 127.f);
      q[qq*4+1] = __float2int_rn(fmaxf(0.f, 1.f - fabsf(xv - ca.y)) * 127.f);
      q[qq*4+2] = __float2int_rn(fmaxf(0.f, 1.f - fabsf(xv - ca.z)) * 127.f);
      q[qq*4+3] = __float2int_rn(fmaxf(0.f, 1.f - fabsf(xv - ca.w)) * 127.f);
    }
    int4 o;
    o.x = pack4(q[0],  q[1],  q[2],  q[3]);
    o.y = pack4(q[4],  q[5],  q[6],  q[7]);
    o.z = pack4(q[8],  q[9],  q[10], q[11]);
    o.w = pack4(q[12], q[13], q[14], q[15]);
    ((int4*)zr)[j] = o;
  }
  float yd = xn0*s4.x + xn1*s4.y + xn2*s4.z + xn3*s4.w;
  #pragma unroll
  for (int off = 32; off > 0; off >>= 1) yd += __shfl_xor(yd, off);
  __syncthreads();
  if ((tid & 63) == 0) red[tid>>6] = yd;
  __syncthreads();
  if (tid == 0) ylin[b] = red[0]+red[1]+red[2]+red[3] + sh_b[0];
}

// fc1_w fp32 -> i8 with per-row scale (row-major wq). One block per row.
__global__ __launch_bounds__(256)
void cvt_kernel(const float* __restrict__ w, unsigned char* __restrict__ wq,
                float* __restrict__ wscale) {
  __shared__ float red[4];
  const int j = blockIdx.x, tid = threadIdx.x;
  const float4* row4 = (const float4*)(w + (size_t)j * KK);
  float4 vv[16];
  float mx = 0.f;
  #pragma unroll
  for (int i = 0; i < 16; ++i) {
    vv[i] = row4[tid + i * 256];
    mx = fmaxf(mx, fmaxf(fmaxf(fabsf(vv[i].x), fabsf(vv[i].y)),
                         fmaxf(fabsf(vv[i].z), fabsf(vv[i].w))));
  }
  #pragma unroll
  for (int off = 32; off > 0; off >>= 1) mx = fmaxf(mx, __shfl_xor(mx, off));
  if ((tid & 63) == 0) red[tid >> 6] = mx;
  __syncthreads();
  const float smax = fmaxf(fmaxf(red[0], red[1]), fmaxf(red[2], red[3]));
  const float inv  = (smax > 0.f) ? 127.f / smax : 0.f;
  if (tid == 0) wscale[j] = smax * (1.f / 127.f);
  int* orow = (int*)(wq + (size_t)j * KK);
  #pragma unroll
  for (int i = 0; i < 16; ++i) {
    const int q0 = __float2int_rn(vv[i].x * inv);
    const int q1 = __float2int_rn(vv[i].y * inv);
    const int q2 = __float2int_rn(vv[i].z * inv);
    const int q3 = __float2int_rn(vv[i].w * inv);
    orow[tid + i * 256] = pack4(q0, q1, q2, q3);
  }
}

// wq (row-major [2048][16384]) -> wt fragment-major:
// wt[((nt*1024 + kc)*16 + r)*16 + b] = wq[nt*16 + r][kc*16 + b]
// so a wave's B-fragment load (16 rows x 4 chunks) is one contiguous 1 KB.
__global__ __launch_bounds__(256)
void trans_kernel(const unsigned char* __restrict__ wq, unsigned char* __restrict__ wt) {
  __shared__ __align__(16) unsigned char tl[16 * 128 * 16];   // [r][kcl] 16B slots, 32 KB
  const int nt   = blockIdx.x >> 3;     // 0..127
  const int ksec = blockIdx.x & 7;      // 0..7 (128 chunks each)
  const int tid  = threadIdx.x;
  #pragma unroll
  for (int j = 0; j < 8; ++j) {
    const int id = tid + 256 * j;
    const int r = id >> 7, kcl = id & 127;
    const int4 v = *reinterpret_cast<const int4*>(
        &wq[(size_t)(nt * 16 + r) * KK + (size_t)(ksec * 128 + kcl) * 16]);
    *reinterpret_cast<int4*>(&tl[(r * 128 + kcl) * 16]) = v;
  }
  __syncthreads();
  const int kcl = tid >> 1, hh = tid & 1;
  int4 o[8];
  #pragma unroll
  for (int r = 0; r < 8; ++r)
    o[r] = *reinterpret_cast<const int4*>(&tl[((hh * 8 + r) * 128 + kcl) * 16]);
  unsigned char* dst = wt + (size_t)(nt * 1024 + ksec * 128 + kcl) * 256 + hh * 128;
  #pragma unroll
  for (int r = 0; r < 8; ++r)
    *reinterpret_cast<int4*>(&dst[r * 16]) = o[r];
}

// h = gelu( (zq @ wq^T) * scale + fc1_b ), bf16 out.
// i8 BK=128, 128x128 tile, 4 waves of 64x64, exact i32 accumulation.
// A: LDS double-buffer (gload_lds + XOR swizzle) — 32 KB LDS only.
// B: NO LDS — fragment-major wt, one contiguous 1KB register load per
//    (n,ks) per wave, ping-pong bA/bB sets prefetched one tile ahead.
// This halves the additive LDS-pipe term that bounded R2..R10.
__global__ __launch_bounds__(256, 2)
void gemm_kernel(const unsigned char* __restrict__ zq, const unsigned char* __restrict__ wt,
                 const float* __restrict__ wscale, const float* __restrict__ fc1_b,
                 unsigned short* __restrict__ h) {
  __shared__ unsigned char As[2][128 * 128];   // 32 KB total
  const int tid  = threadIdx.x;
  const int lane = tid & 63;
  const int wv   = tid >> 6;
  // bijective XCD swizzle (512 % 8 == 0): XCD k gets bids k*64..k*64+63
  const int bid = (blockIdx.x & 7) * 64 + (blockIdx.x >> 3);
  const int bm = bid & 31;     // M/128 = 32 (fastest)
  const int bn = bid >> 5;     // N/128 = 16
  const int wr = wv >> 1, wc = wv & 1;

  i32x4 acc[4][4];
  #pragma unroll
  for (int m = 0; m < 4; ++m)
    #pragma unroll
    for (int n = 0; n < 4; ++n)
      acc[m][n] = (i32x4){0, 0, 0, 0};

  const int srow   = lane >> 3;            // row-in-8 for A staging
  const int schunk = (lane & 7) ^ srow;    // pre-swizzled source 16B chunk
  const int frow = lane & 15;
  const int fkb  = lane >> 4;              // 0..3

  const unsigned char* zb  = zq + (size_t)(bm * 128) * KK;
  // wt panel for this wave's 4 n-tiles: nt_g = bn*8 + wc*4 + n
  const unsigned char* wtb = wt + (size_t)(bn * 8 + wc * 4) * 262144;  // 1024*256

  #define STAGE_A(buf, t) do { \
    const int k0_ = (t) * 128; \
    _Pragma("unroll") \
    for (int i_ = 0; i_ < 4; ++i_) { \
      const int r_ = i_ * 32 + wv * 8 + srow; \
      __builtin_amdgcn_global_load_lds( \
          (const __attribute__((address_space(1))) void*)(zb + (size_t)r_ * KK + k0_ + schunk * 16), \
          (__attribute__((address_space(3))) void*)(&As[buf][(i_ * 32 + wv * 8) * 128]), 16, 0, 0); \
    } \
  } while (0)

  // load B fragments for tile t: 8 contiguous-1KB wave loads (lane*16)
  #define LOADB(dst, t) do { \
    _Pragma("unroll") \
    for (int n_ = 0; n_ < 4; ++n_) { \
      _Pragma("unroll") \
      for (int ks_ = 0; ks_ < 2; ++ks_) { \
        dst[n_][ks_] = *reinterpret_cast<const i32x4*>( \
            &wtb[(size_t)n_ * 262144 + (size_t)((t) * 8 + ks_ * 4) * 256 + lane * 16]); \
      } \
    } \
  } while (0)

  #define COMPUTE(buf, bset) do { \
    _Pragma("unroll") \
    for (int ks_ = 0; ks_ < 2; ++ks_) { \
      const int kb_ = ks_ * 4 + fkb; \
      i32x4 af_[4]; \
      _Pragma("unroll") \
      for (int m_ = 0; m_ < 4; ++m_) { \
        const int Ra_ = wr * 64 + m_ * 16 + frow; \
        af_[m_] = *reinterpret_cast<const i32x4*>(&As[buf][Ra_ * 128 + ((kb_ ^ (Ra_ & 7)) * 16)]); \
      } \
      _Pragma("unroll") \
      for (int m_ = 0; m_ < 4; ++m_) \
        _Pragma("unroll") \
        for (int n_ = 0; n_ < 4; ++n_) \
          acc[m_][n_] = __builtin_amdgcn_mfma_i32_16x16x64_i8(af_[m_], bset[n_][ks_], acc[m_][n_], 0, 0, 0); \
    } \
  } while (0)

  i32x4 bA[4][2], bB[4][2];   // named ping-pong B sets (static indexing)

  STAGE_A(0, 0);
  LOADB(bA, 0);

  for (int t = 0; t < NT; t += 2) {
    // half 1: compute tile t (As[0], bA); prefetch t+1
    __syncthreads();                  // drains stage/loads of tile t
    STAGE_A(1, t + 1);                // t+1 <= 127 always
    LOADB(bB, t + 1);
    COMPUTE(0, bA);
    // half 2: compute tile t+1 (As[1], bB); prefetch t+2
    __syncthreads();
    if (t + 2 < NT) {
      STAGE_A(0, t + 2);
      LOADB(bA, t + 2);
    }
    COMPUTE(1, bB);
  }
  #undef STAGE_A
  #undef LOADB
  #undef COMPUTE

  // epilogue: h = gelu(acc * (wscale[col]/127) + bias), bf16.
  // C/D: col=lane&15, row=(lane>>4)*4+reg
  const int row0 = bm * 128 + wr * 64;
  const int col0 = bn * 128 + wc * 64;
  #pragma unroll
  for (int n = 0; n < 4; ++n) {
    const int col = col0 + n * 16 + frow;
    const float sc   = wscale[col] * (1.f / 127.f);
    const float bias = fc1_b[col];
    #pragma unroll
    for (int m = 0; m < 4; ++m) {
      #pragma unroll
      for (int r = 0; r < 4; ++r) {
        const int row = row0 + m * 16 + fkb * 4 + r;
        const float xg = (float)acc[m][n][r] * sc + bias;
        h[(size_t)row * HH + col] = f2bf(0.5f * xg * (1.f + erff(xg * 0.70710678118f)));
      }
    }
  }
}

// out[b] = dot(h[b], hm_w) + hm_b + relu(gamma)*ylin[b];  out[BB+b] = dot(h[b], hv_w) + hv_b
__global__ __launch_bounds__(256)
void head_kernel(const unsigned short* __restrict__ h, const float* __restrict__ hm_w,
                 const float* __restrict__ hm_b, const float* __restrict__ hv_w,
                 const float* __restrict__ hv_b, const float* __restrict__ ylin,
                 const float* __restrict__ gamma, float* __restrict__ out) {
  __shared__ float red[8];
  const int b = blockIdx.x, tid = threadIdx.x;
  const us8 hv8 = ((const us8*)(h + (size_t)b * HH))[tid];
  const float4 m0 = ((const float4*)hm_w)[tid*2],  m1 = ((const float4*)hm_w)[tid*2+1];
  const float4 v0 = ((const float4*)hv_w)[tid*2],  v1 = ((const float4*)hv_w)[tid*2+1];
  float hf[8];
  #pragma unroll
  for (int i = 0; i < 8; ++i) hf[i] = bf2f((unsigned short)hv8[i]);
  float dm = hf[0]*m0.x + hf[1]*m0.y + hf[2]*m0.z + hf[3]*m0.w
           + hf[4]*m1.x + hf[5]*m1.y + hf[6]*m1.z + hf[7]*m1.w;
  float dv = hf[0]*v0.x + hf[1]*v0.y + hf[2]*v0.z + hf[3]*v0.w
           + hf[4]*v1.x + hf[5]*v1.y + hf[6]*v1.z + hf[7]*v1.w;
  #pragma unroll
  for (int off = 32; off > 0; off >>= 1) {
    dm += __shfl_xor(dm, off);
    dv += __shfl_xor(dv, off);
  }
  if ((tid & 63) == 0) { red[(tid>>6)*2] = dm; red[(tid>>6)*2+1] = dv; }
  __syncthreads();
  if (tid == 0) {
    const float sm = red[0]+red[2]+red[4]+red[6] + hm_b[0];
    const float sv = red[1]+red[3]+red[5]+red[7] + hv_b[0];
    out[b]      = sm + fmaxf(gamma[0], 0.f) * ylin[b];
    out[BB + b] = sv;
  }
}

extern "C" void kernel_launch(void* const* d_in, const int* in_sizes, int n_in,
                              void* d_out, int out_size, void* d_ws, size_t ws_size,
                              hipStream_t stream) {
  const float* x       = (const float*)d_in[0];
  const float* ln_g    = (const float*)d_in[1];
  const float* ln_b    = (const float*)d_in[2];
  const float* centers = (const float*)d_in[3];
  const float* width   = (const float*)d_in[4];
  const float* fc1_w   = (const float*)d_in[5];
  const float* fc1_b   = (const float*)d_in[6];
  const float* hm_w    = (const float*)d_in[7];
  const float* hm_b    = (const float*)d_in[8];
  const float* hv_w    = (const float*)d_in[9];
  const float* hv_b    = (const float*)d_in[10];
  const float* sh_w    = (const float*)d_in[11];
  const float* sh_b    = (const float*)d_in[12];
  const float* gamma   = (const float*)d_in[13];

  char* ws = (char*)d_ws;
  // ws: cs 64KB @0 | ylin 16KB @64KB | wscale 8KB @80KB |
  //     zq 64MB @1MB | wq 32MB @65MB | wt 32MB @97MB | h(bf16) 16MB @129MB
  float* cs            = (float*)(ws);
  float* ylin          = (float*)(ws + (64 << 10));
  float* wscale        = (float*)(ws + (80 << 10));
  unsigned char* zq    = (unsigned char*)(ws + (1ull << 20));
  unsigned char* wq    = (unsigned char*)(ws + (65ull << 20));
  unsigned char* wt    = (unsigned char*)(ws + (97ull << 20));
  unsigned short* h    = (unsigned short*)(ws + (129ull << 20));
  float* out           = (float*)d_out;

  prep_kernel <<<dim3(64),   dim3(256), 0, stream>>>(centers, width, cs);
  zexp_kernel <<<dim3(4096), dim3(256), 0, stream>>>(x, ln_g, ln_b, width, sh_w, sh_b, cs, zq, ylin);
  cvt_kernel  <<<dim3(2048), dim3(256), 0, stream>>>(fc1_w, wq, wscale);
  trans_kernel<<<dim3(1024), dim3(256), 0, stream>>>(wq, wt);
  gemm_kernel <<<dim3(512),  dim3(256), 0, stream>>>(zq, wt, wscale, fc1_b, h);
  head_kernel <<<dim3(4096), dim3(256), 0, stream>>>(h, hm_w, hm_b, hv_w, hv_b, ylin, gamma, out);
}

// Round 12
// 241.561 us; speedup vs baseline: 1.1254x; 1.1254x over previous
//
#include <hip/hip_runtime.h>
#include <hip/hip_bf16.h>

#define BB 4096
#define DD 1024
#define NBF 16
#define HH 2048
#define KK 16384   // DD*NBF (elements; also bytes for i8 rows)
#define NT 128     // K-tiles of 128 bytes
#define LN_EPS 1e-5f

typedef int   i32x4  __attribute__((ext_vector_type(4)));    // i8 MFMA A/B (16 i8)
typedef int   i32x16 __attribute__((ext_vector_type(16)));   // 32x32 C/D (16 i32)
typedef unsigned short us8 __attribute__((ext_vector_type(8)));

__device__ __forceinline__ unsigned short f2bf(float f) {
  union { float f; unsigned int u; } c; c.f = f;
  unsigned int u = c.u;
  return (unsigned short)((u + 0x7FFFu + ((u >> 16) & 1u)) >> 16);  // RNE
}
__device__ __forceinline__ float bf2f(unsigned short s) {
  union { unsigned int u; float f; } c; c.u = ((unsigned int)s) << 16;
  return c.f;
}
__device__ __forceinline__ float softplusf(float x) {
  return (x > 20.f) ? x : log1pf(expf(x));
}
__device__ __forceinline__ int pack4(int q0, int q1, int q2, int q3) {
  return (q0 & 0xff) | ((q1 & 0xff) << 8) | ((q2 & 0xff) << 16) | ((q3 & 0xff) << 24);
}

// cs[d*16+k] = centers[d][k] / (softplus(width[d]) + 1e-6)
__global__ void prep_kernel(const float* __restrict__ centers, const float* __restrict__ width,
                            float* __restrict__ cs) {
  const int i = blockIdx.x * 256 + threadIdx.x;  // 16384 total
  const int d = i >> 4;
  const float w = softplusf(width[d]) + 1e-6f;
  cs[i] = centers[i] / w;
}

// LayerNorm + triangular basis -> zq (i8 [B,KK], zq = round(127*phi)), and ylin[b]
__global__ __launch_bounds__(256)
void zexp_kernel(const float* __restrict__ x, const float* __restrict__ g,
                 const float* __restrict__ be, const float* __restrict__ width,
                 const float* __restrict__ sh_w, const float* __restrict__ sh_b,
                 const float* __restrict__ cs,
                 unsigned char* __restrict__ zq, float* __restrict__ ylin) {
  __shared__ float red[8];
  const int b = blockIdx.x, tid = threadIdx.x;
  const float4 v = ((const float4*)(x + (size_t)b * DD))[tid];
  float s  = v.x + v.y + v.z + v.w;
  float ss = v.x*v.x + v.y*v.y + v.z*v.z + v.w*v.w;
  #pragma unroll
  for (int off = 32; off > 0; off >>= 1) {
    s  += __shfl_xor(s, off);
    ss += __shfl_xor(ss, off);
  }
  if ((tid & 63) == 0) { red[(tid>>6)*2] = s; red[(tid>>6)*2+1] = ss; }
  __syncthreads();
  const float sum   = red[0]+red[2]+red[4]+red[6];
  const float sumsq = red[1]+red[3]+red[5]+red[7];
  const float mu   = sum * (1.f/DD);
  const float var  = sumsq * (1.f/DD) - mu*mu;
  const float rstd = rsqrtf(var + LN_EPS);
  const float4 g4 = ((const float4*)g)[tid];
  const float4 b4 = ((const float4*)be)[tid];
  const float4 w4 = ((const float4*)width)[tid];
  const float4 s4 = ((const float4*)sh_w)[tid];
  const float xn0 = (v.x - mu)*rstd*g4.x + b4.x;
  const float xn1 = (v.y - mu)*rstd*g4.y + b4.y;
  const float xn2 = (v.z - mu)*rstd*g4.z + b4.z;
  const float xn3 = (v.w - mu)*rstd*g4.w + b4.w;
  float xsv[4];
  xsv[0] = xn0 / (softplusf(w4.x) + 1e-6f);
  xsv[1] = xn1 / (softplusf(w4.y) + 1e-6f);
  xsv[2] = xn2 / (softplusf(w4.z) + 1e-6f);
  xsv[3] = xn3 / (softplusf(w4.w) + 1e-6f);
  // thread owns d = tid*4..+3 -> 64 contiguous i8 (16 per d)
  unsigned char* zr = zq + (size_t)b * KK + tid * 64;
  #pragma unroll
  for (int j = 0; j < 4; ++j) {
    const float4* c4 = (const float4*)(cs + (tid * 4 + j) * 16);
    const float xv = xsv[j];
    int q[16];
    #pragma unroll
    for (int qq = 0; qq < 4; ++qq) {
      const float4 ca = c4[qq];
      q[qq*4+0] = __float2int_rn(fmaxf(0.f, 1.f - fabsf(xv - ca.x)) * 127.f);
      q[qq*4+1] = __float2int_rn(fmaxf(0.f, 1.f - fabsf(xv - ca.y)) * 127.f);
      q[qq*4+2] = __float2int_rn(fmaxf(0.f, 1.f - fabsf(xv - ca.z)) * 127.f);
      q[qq*4+3] = __float2int_rn(fmaxf(0.f, 1.f - fabsf(xv - ca.w)) * 127.f);
    }
    int4 o;
    o.x = pack4(q[0],  q[1],  q[2],  q[3]);
    o.y = pack4(q[4],  q[5],  q[6],  q[7]);
    o.z = pack4(q[8],  q[9],  q[10], q[11]);
    o.w = pack4(q[12], q[13], q[14], q[15]);
    ((int4*)zr)[j] = o;
  }
  float yd = xn0*s4.x + xn1*s4.y + xn2*s4.z + xn3*s4.w;
  #pragma unroll
  for (int off = 32; off > 0; off >>= 1) yd += __shfl_xor(yd, off);
  __syncthreads();
  if ((tid & 63) == 0) red[tid>>6] = yd;
  __syncthreads();
  if (tid == 0) ylin[b] = red[0]+red[1]+red[2]+red[3] + sh_b[0];
}

// fc1_w fp32 -> i8 with per-row scale. One block per row j; row held in regs.
__global__ __launch_bounds__(256)
void cvt_kernel(const float* __restrict__ w, unsigned char* __restrict__ wq,
                float* __restrict__ wscale) {
  __shared__ float red[4];
  const int j = blockIdx.x, tid = threadIdx.x;
  const float4* row4 = (const float4*)(w + (size_t)j * KK);
  float4 vv[16];
  float mx = 0.f;
  #pragma unroll
  for (int i = 0; i < 16; ++i) {
    vv[i] = row4[tid + i * 256];
    mx = fmaxf(mx, fmaxf(fmaxf(fabsf(vv[i].x), fabsf(vv[i].y)),
                         fmaxf(fabsf(vv[i].z), fabsf(vv[i].w))));
  }
  #pragma unroll
  for (int off = 32; off > 0; off >>= 1) mx = fmaxf(mx, __shfl_xor(mx, off));
  if ((tid & 63) == 0) red[tid >> 6] = mx;
  __syncthreads();
  const float smax = fmaxf(fmaxf(red[0], red[1]), fmaxf(red[2], red[3]));
  const float inv  = (smax > 0.f) ? 127.f / smax : 0.f;
  if (tid == 0) wscale[j] = smax * (1.f / 127.f);
  int* orow = (int*)(wq + (size_t)j * KK);
  #pragma unroll
  for (int i = 0; i < 16; ++i) {
    const int q0 = __float2int_rn(vv[i].x * inv);
    const int q1 = __float2int_rn(vv[i].y * inv);
    const int q2 = __float2int_rn(vv[i].z * inv);
    const int q3 = __float2int_rn(vv[i].w * inv);
    orow[tid + i * 256] = pack4(q0, q1, q2, q3);
  }
}

// h = gelu( (zq @ wq^T) * scale + fc1_b ), bf16 out.
// R7 structure verbatim (best measured base: i8 BK=128, 128x128 tile, 4 waves
// of 64x64, dbuf LDS, one __syncthreads per K-iter) with ONE change: MFMA
// shape 16x16x64 -> 32x32x32. Wave tile = 2x2 tiles of 32x32; 16 MFMA/iter
// (was 32) at 65536 ops each; LDS traffic identical (16 ds_read_b128/iter).
// A/B operand: lane l holds row/col (l&31), k = ks*32 + (l>>5)*16 (16B frag).
// C/D: col=lane&31, row=(reg&3)+8*(reg>>2)+4*(lane>>5)  [m74/m101 verified].
__global__ __launch_bounds__(256, 2)
void gemm_kernel(const unsigned char* __restrict__ zq, const unsigned char* __restrict__ wq,
                 const float* __restrict__ wscale, const float* __restrict__ fc1_b,
                 unsigned short* __restrict__ h) {
  __shared__ unsigned char As[2][128 * 128];   // 32 KB
  __shared__ unsigned char Bs[2][128 * 128];   // 32 KB
  const int tid  = threadIdx.x;
  const int lane = tid & 63;
  const int wv   = tid >> 6;
  // bijective XCD swizzle (512 % 8 == 0)
  const int bid = (blockIdx.x & 7) * 64 + (blockIdx.x >> 3);
  const int bm = bid & 31;     // M/128 = 32 (fastest -> consecutive blocks share B panel)
  const int bn = bid >> 5;     // N/128 = 16
  const int wr = wv >> 1, wc = wv & 1;

  i32x16 acc[2][2];
  #pragma unroll
  for (int m = 0; m < 2; ++m)
    #pragma unroll
    for (int n = 0; n < 2; ++n)
      #pragma unroll
      for (int r = 0; r < 16; ++r)
        acc[m][n][r] = 0;

  const int srow   = lane >> 3;            // row-in-8 for staging
  const int schunk = (lane & 7) ^ srow;    // pre-swizzled source 16B chunk (of 8/row)
  const int frow = lane & 31;              // fragment row/col within 32-tile
  const int fhi  = lane >> 5;              // k-half selector (0/1)

  const unsigned char* zb  = zq + (size_t)(bm * 128) * KK;
  const unsigned char* wbb = wq + (size_t)(bn * 128) * KK;

  #define STAGE(buf, t) do { \
    const int k0_ = (t) * 128; \
    _Pragma("unroll") \
    for (int i_ = 0; i_ < 4; ++i_) { \
      const int r_ = i_ * 32 + wv * 8 + srow; \
      __builtin_amdgcn_global_load_lds( \
          (const __attribute__((address_space(1))) void*)(zb + (size_t)r_ * KK + k0_ + schunk * 16), \
          (__attribute__((address_space(3))) void*)(&As[buf][(i_ * 32 + wv * 8) * 128]), 16, 0, 0); \
      __builtin_amdgcn_global_load_lds( \
          (const __attribute__((address_space(1))) void*)(wbb + (size_t)r_ * KK + k0_ + schunk * 16), \
          (__attribute__((address_space(3))) void*)(&Bs[buf][(i_ * 32 + wv * 8) * 128]), 16, 0, 0); \
    } \
  } while (0)

  STAGE(0, 0);   // prologue: tile 0 into buf 0

  for (int t = 0; t < NT; ++t) {
    __syncthreads();   // drains vmcnt: tile t resident; buf[(t+1)&1] reads retired
    if (t + 1 < NT) STAGE((t + 1) & 1, t + 1);
    const unsigned char* Ac = &As[t & 1][0];
    const unsigned char* Bc = &Bs[t & 1][0];
    #pragma unroll
    for (int ks = 0; ks < 4; ++ks) {                  // K=32 per MFMA, 4 per 128-B row
      const int kb = ks * 2 + fhi;                    // 16-B chunk index 0..7
      i32x4 af[2], bfr[2];
      #pragma unroll
      for (int m = 0; m < 2; ++m) {
        const int Ra = wr * 64 + m * 32 + frow;
        af[m] = *reinterpret_cast<const i32x4*>(&Ac[Ra * 128 + ((kb ^ (Ra & 7)) * 16)]);
      }
      #pragma unroll
      for (int n = 0; n < 2; ++n) {
        const int Rb = wc * 64 + n * 32 + frow;
        bfr[n] = *reinterpret_cast<const i32x4*>(&Bc[Rb * 128 + ((kb ^ (Rb & 7)) * 16)]);
      }
      #pragma unroll
      for (int m = 0; m < 2; ++m)
        #pragma unroll
        for (int n = 0; n < 2; ++n)
          acc[m][n] = __builtin_amdgcn_mfma_i32_32x32x32_i8(af[m], bfr[n], acc[m][n], 0, 0, 0);
    }
  }
  #undef STAGE

  // epilogue: h = gelu(acc * (wscale[col]/127) + bias), bf16.
  // 32x32 C/D: col=lane&31, row=(reg&3)+8*(reg>>2)+4*(lane>>5)
  const int row0 = bm * 128 + wr * 64;
  const int col0 = bn * 128 + wc * 64;
  #pragma unroll
  for (int n = 0; n < 2; ++n) {
    const int col = col0 + n * 32 + frow;
    const float sc   = wscale[col] * (1.f / 127.f);
    const float bias = fc1_b[col];
    #pragma unroll
    for (int m = 0; m < 2; ++m) {
      #pragma unroll
      for (int r = 0; r < 16; ++r) {
        const int row = row0 + m * 32 + (r & 3) + 8 * (r >> 2) + 4 * fhi;
        const float xg = (float)acc[m][n][r] * sc + bias;
        h[(size_t)row * HH + col] = f2bf(0.5f * xg * (1.f + erff(xg * 0.70710678118f)));
      }
    }
  }
}

// out[b] = dot(h[b], hm_w) + hm_b + relu(gamma)*ylin[b];  out[BB+b] = dot(h[b], hv_w) + hv_b
__global__ __launch_bounds__(256)
void head_kernel(const unsigned short* __restrict__ h, const float* __restrict__ hm_w,
                 const float* __restrict__ hm_b, const float* __restrict__ hv_w,
                 const float* __restrict__ hv_b, const float* __restrict__ ylin,
                 const float* __restrict__ gamma, float* __restrict__ out) {
  __shared__ float red[8];
  const int b = blockIdx.x, tid = threadIdx.x;
  const us8 hv8 = ((const us8*)(h + (size_t)b * HH))[tid];
  const float4 m0 = ((const float4*)hm_w)[tid*2],  m1 = ((const float4*)hm_w)[tid*2+1];
  const float4 v0 = ((const float4*)hv_w)[tid*2],  v1 = ((const float4*)hv_w)[tid*2+1];
  float hf[8];
  #pragma unroll
  for (int i = 0; i < 8; ++i) hf[i] = bf2f((unsigned short)hv8[i]);
  float dm = hf[0]*m0.x + hf[1]*m0.y + hf[2]*m0.z + hf[3]*m0.w
           + hf[4]*m1.x + hf[5]*m1.y + hf[6]*m1.z + hf[7]*m1.w;
  float dv = hf[0]*v0.x + hf[1]*v0.y + hf[2]*v0.z + hf[3]*v0.w
           + hf[4]*v1.x + hf[5]*v1.y + hf[6]*v1.z + hf[7]*v1.w;
  #pragma unroll
  for (int off = 32; off > 0; off >>= 1) {
    dm += __shfl_xor(dm, off);
    dv += __shfl_xor(dv, off);
  }
  if ((tid & 63) == 0) { red[(tid>>6)*2] = dm; red[(tid>>6)*2+1] = dv; }
  __syncthreads();
  if (tid == 0) {
    const float sm = red[0]+red[2]+red[4]+red[6] + hm_b[0];
    const float sv = red[1]+red[3]+red[5]+red[7] + hv_b[0];
    out[b]      = sm + fmaxf(gamma[0], 0.f) * ylin[b];
    out[BB + b] = sv;
  }
}

extern "C" void kernel_launch(void* const* d_in, const int* in_sizes, int n_in,
                              void* d_out, int out_size, void* d_ws, size_t ws_size,
                              hipStream_t stream) {
  const float* x       = (const float*)d_in[0];
  const float* ln_g    = (const float*)d_in[1];
  const float* ln_b    = (const float*)d_in[2];
  const float* centers = (const float*)d_in[3];
  const float* width   = (const float*)d_in[4];
  const float* fc1_w   = (const float*)d_in[5];
  const float* fc1_b   = (const float*)d_in[6];
  const float* hm_w    = (const float*)d_in[7];
  const float* hm_b    = (const float*)d_in[8];
  const float* hv_w    = (const float*)d_in[9];
  const float* hv_b    = (const float*)d_in[10];
  const float* sh_w    = (const float*)d_in[11];
  const float* sh_b    = (const float*)d_in[12];
  const float* gamma   = (const float*)d_in[13];

  char* ws = (char*)d_ws;
  // ws: cs 64KB @0 | ylin 16KB @64KB | wscale 8KB @80KB | zq 64MB @1MB | wq 32MB @65MB | h(bf16) 16MB @97MB
  float* cs            = (float*)(ws);
  float* ylin          = (float*)(ws + (64 << 10));
  float* wscale        = (float*)(ws + (80 << 10));
  unsigned char* zq    = (unsigned char*)(ws + (1ull << 20));
  unsigned char* wq    = (unsigned char*)(ws + (65ull << 20));
  unsigned short* h    = (unsigned short*)(ws + (97ull << 20));
  float* out           = (float*)d_out;

  prep_kernel<<<dim3(64),   dim3(256), 0, stream>>>(centers, width, cs);
  zexp_kernel<<<dim3(4096), dim3(256), 0, stream>>>(x, ln_g, ln_b, width, sh_w, sh_b, cs, zq, ylin);
  cvt_kernel <<<dim3(2048), dim3(256), 0, stream>>>(fc1_w, wq, wscale);
  gemm_kernel<<<dim3(512),  dim3(256), 0, stream>>>(zq, wq, wscale, fc1_b, h);
  head_kernel<<<dim3(4096), dim3(256), 0, stream>>>(h, hm_w, hm_b, hv_w, hv_b, ylin, gamma, out);
}